// Round 3
// baseline (794.562 us; speedup 1.0000x reference)
//
#include <hip/hip_runtime.h>
#include <hip/hip_bf16.h>

#define BATCH 16
#define SEQ   2048
#define DIM   128
#define NEL   (BATCH * SEQ * DIM)          // 4,194,304 elements per plane
#define SCALE 0.08838834764831845f         // 1/sqrt(128)

typedef __attribute__((ext_vector_type(8))) short short8;
typedef __attribute__((ext_vector_type(4))) float f32x4;
typedef unsigned short ushort_t;

__device__ __forceinline__ unsigned short f2bf(float x) {
    unsigned int u = __float_as_uint(x);
    u += 0x7fffu + ((u >> 16) & 1u);   // round-to-nearest-even
    return (unsigned short)(u >> 16);
}
__device__ __forceinline__ float bf2f(unsigned short h) {
    return __uint_as_float(((unsigned int)h) << 16);
}
__device__ __forceinline__ void cvt_hl(float x, unsigned short& h, unsigned short& l) {
    h = f2bf(x);
    l = f2bf(x - bf2f(h));             // hi+lo together ~17 mantissa bits
}

// ---------------------------------------------------------------------------
// P0: split Q and K into planar bf16 hi/lo arrays (row-major, same layout).
// ---------------------------------------------------------------------------
__global__ __launch_bounds__(256) void split_qk_kernel(
    const float* __restrict__ Q, const float* __restrict__ K,
    ushort_t* __restrict__ Qh, ushort_t* __restrict__ Ql,
    ushort_t* __restrict__ Kh, ushort_t* __restrict__ Kl)
{
    size_t base = ((size_t)blockIdx.x * 256 + threadIdx.x) * 4;
    float4 q = *(const float4*)(Q + base);
    ushort4 H, L;
    cvt_hl(q.x, H.x, L.x); cvt_hl(q.y, H.y, L.y);
    cvt_hl(q.z, H.z, L.z); cvt_hl(q.w, H.w, L.w);
    *(ushort4*)(Qh + base) = H;
    *(ushort4*)(Ql + base) = L;
    float4 k = *(const float4*)(K + base);
    cvt_hl(k.x, H.x, L.x); cvt_hl(k.y, H.y, L.y);
    cvt_hl(k.z, H.z, L.z); cvt_hl(k.w, H.w, L.w);
    *(ushort4*)(Kh + base) = H;
    *(ushort4*)(Kl + base) = L;
}

// ---------------------------------------------------------------------------
// P1: transpose-split V[b][s][d] -> VT[b][d][s] bf16 hi/lo planes.
// 64x64 tiles through LDS (stride 65 -> conflict-free both phases).
// ---------------------------------------------------------------------------
__global__ __launch_bounds__(256) void split_vt_kernel(
    const float* __restrict__ V,
    ushort_t* __restrict__ VTh, ushort_t* __restrict__ VTl)
{
    __shared__ float tile[64 * 65];
    const int s0 = blockIdx.x * 64, d0 = blockIdx.y * 64, b = blockIdx.z;
    const int t = threadIdx.x;
#pragma unroll
    for (int it = 0; it < 4; ++it) {
        int i = t + 256 * it;
        int row = i >> 4, c4 = i & 15;
        float4 v4 = *(const float4*)(V + ((size_t)(b * SEQ + s0 + row)) * DIM + d0 + c4 * 4);
        tile[row * 65 + c4 * 4 + 0] = v4.x;
        tile[row * 65 + c4 * 4 + 1] = v4.y;
        tile[row * 65 + c4 * 4 + 2] = v4.z;
        tile[row * 65 + c4 * 4 + 3] = v4.w;
    }
    __syncthreads();
#pragma unroll
    for (int it = 0; it < 4; ++it) {
        int i = t + 256 * it;
        int dr = i >> 4, s4 = i & 15;
        ushort4 H, L;
        unsigned short h, l;
        cvt_hl(tile[(s4 * 4 + 0) * 65 + dr], h, l); H.x = h; L.x = l;
        cvt_hl(tile[(s4 * 4 + 1) * 65 + dr], h, l); H.y = h; L.y = l;
        cvt_hl(tile[(s4 * 4 + 2) * 65 + dr], h, l); H.z = h; L.z = l;
        cvt_hl(tile[(s4 * 4 + 3) * 65 + dr], h, l); H.w = h; L.w = l;
        size_t ofs = ((size_t)(b * DIM + d0 + dr)) * SEQ + s0 + s4 * 4;
        *(ushort4*)(VTh + ofs) = H;
        *(ushort4*)(VTl + ofs) = L;
    }
}

// ---------------------------------------------------------------------------
// K1: E = exp(scale * Q.K^T) (unnormalized attn), lsum += row sums.
// LDS-free: MFMA fragments loaded directly from pre-split bf16 planes
// (fragment layout == contiguous 16B row chunks). No barriers.
// Grid (16 kt, 16 qt, 16 b), 256 thr, 4 waves 2x2, wave = 64x64 out.
// ---------------------------------------------------------------------------
__global__ __launch_bounds__(256) void attn_scores_kernel(
    const ushort_t* __restrict__ Qh, const ushort_t* __restrict__ Ql,
    const ushort_t* __restrict__ Kh, const ushort_t* __restrict__ Kl,
    float* __restrict__ E, float* __restrict__ lsum)
{
    const int kt = blockIdx.x, qt = blockIdx.y, b = blockIdx.z;
    const int t = threadIdx.x;
    const int lane = t & 63, wave = t >> 6;
    const int quad = lane >> 4, l15 = lane & 15;
    const int wr = wave >> 1, wc = wave & 1;

    f32x4 acc[4][4];
#pragma unroll
    for (int i = 0; i < 4; ++i)
#pragma unroll
        for (int j = 0; j < 4; ++j)
            acc[i][j] = (f32x4){0.f, 0.f, 0.f, 0.f};

    const size_t qrow0 = (size_t)(b * SEQ + qt * 128 + wr * 64 + l15) * DIM;
    const size_t krow0 = (size_t)(b * SEQ + kt * 128 + wc * 64 + l15) * DIM;

#pragma unroll 1
    for (int kc = 0; kc < 4; ++kc) {
        const int co = kc * 32 + quad * 8;
        short8 ah[4], al[4], bh[4], bl[4];
#pragma unroll
        for (int i = 0; i < 4; ++i) {
            size_t off = qrow0 + (size_t)(i * 16) * DIM + co;
            ah[i] = *(const short8*)(Qh + off);
            al[i] = *(const short8*)(Ql + off);
        }
#pragma unroll
        for (int j = 0; j < 4; ++j) {
            size_t off = krow0 + (size_t)(j * 16) * DIM + co;
            bh[j] = *(const short8*)(Kh + off);
            bl[j] = *(const short8*)(Kl + off);
        }
#pragma unroll
        for (int i = 0; i < 4; ++i)
#pragma unroll
            for (int j = 0; j < 4; ++j) {
                acc[i][j] = __builtin_amdgcn_mfma_f32_16x16x32_bf16(ah[i], bh[j], acc[i][j], 0, 0, 0);
                acc[i][j] = __builtin_amdgcn_mfma_f32_16x16x32_bf16(ah[i], bl[j], acc[i][j], 0, 0, 0);
                acc[i][j] = __builtin_amdgcn_mfma_f32_16x16x32_bf16(al[i], bh[j], acc[i][j], 0, 0, 0);
            }
    }

    // epilogue: E = exp(scale * s), row-sum -> atomic into lsum
    float* Eb = E + ((size_t)b * SEQ + (size_t)qt * 128 + wr * 64) * SEQ
                  + (size_t)kt * 128 + wc * 64;
    float* Lb = lsum + b * SEQ + qt * 128 + wr * 64;
#pragma unroll
    for (int i = 0; i < 4; ++i) {
        float rs0 = 0.f, rs1 = 0.f, rs2 = 0.f, rs3 = 0.f;
#pragma unroll
        for (int j = 0; j < 4; ++j) {
            f32x4 a = acc[i][j];
            float p0 = __expf(a[0] * SCALE);
            float p1 = __expf(a[1] * SCALE);
            float p2 = __expf(a[2] * SCALE);
            float p3 = __expf(a[3] * SCALE);
            size_t rb = (size_t)(i * 16 + quad * 4) * SEQ + j * 16 + l15;
            Eb[rb]           = p0;
            Eb[rb + SEQ]     = p1;
            Eb[rb + 2 * SEQ] = p2;
            Eb[rb + 3 * SEQ] = p3;
            rs0 += p0; rs1 += p1; rs2 += p2; rs3 += p3;
        }
        rs0 += __shfl_xor(rs0, 1); rs0 += __shfl_xor(rs0, 2);
        rs0 += __shfl_xor(rs0, 4); rs0 += __shfl_xor(rs0, 8);
        rs1 += __shfl_xor(rs1, 1); rs1 += __shfl_xor(rs1, 2);
        rs1 += __shfl_xor(rs1, 4); rs1 += __shfl_xor(rs1, 8);
        rs2 += __shfl_xor(rs2, 1); rs2 += __shfl_xor(rs2, 2);
        rs2 += __shfl_xor(rs2, 4); rs2 += __shfl_xor(rs2, 8);
        rs3 += __shfl_xor(rs3, 1); rs3 += __shfl_xor(rs3, 2);
        rs3 += __shfl_xor(rs3, 4); rs3 += __shfl_xor(rs3, 8);
        if (l15 == 0) {
            atomicAdd(&Lb[i * 16 + quad * 4 + 0], rs0);
            atomicAdd(&Lb[i * 16 + quad * 4 + 1], rs1);
            atomicAdd(&Lb[i * 16 + quad * 4 + 2], rs2);
            atomicAdd(&Lb[i * 16 + quad * 4 + 3], rs3);
        }
    }
}

// ---------------------------------------------------------------------------
// K2: normalize E in place (final weights) + O = P@V, LDS-free.
// A-fragments: read E fp32 (the normalize write-back IS the frag source),
// B-fragments: direct b128 loads from VT planes. O accumulated via f32
// atomics over a k-split of 2 (O pre-zeroed by memset).
// Grid (32 qt, 2 ks, 16 b), 256 thr, 4 waves; wave = 16q x 128d.
// ---------------------------------------------------------------------------
__global__ __launch_bounds__(256) void attn_out_kernel(
    const ushort_t* __restrict__ VTh, const ushort_t* __restrict__ VTl,
    float* __restrict__ E, const float* __restrict__ lsum,
    float* __restrict__ O)
{
    const int qt = blockIdx.x, ks = blockIdx.y, b = blockIdx.z;
    const int t = threadIdx.x;
    const int lane = t & 63, w = t >> 6;
    const int quad = lane >> 4, l15 = lane & 15;

    const int qbase = qt * 64 + w * 16;
    const float rl = 1.0f / lsum[b * SEQ + qbase + l15];

    f32x4 acc[8];
#pragma unroll
    for (int j = 0; j < 8; ++j) acc[j] = (f32x4){0.f, 0.f, 0.f, 0.f};

    float* Ep = E + ((size_t)(b * SEQ + qbase + l15)) * SEQ + ks * 1024;
    const size_t vtrow0 = (size_t)(b * DIM + l15) * SEQ + ks * 1024;

#pragma unroll 1
    for (int kc = 0; kc < 32; ++kc) {
        const int co = kc * 32 + quad * 8;
        float4 e0 = *(const float4*)(Ep + co);
        float4 e1 = *(const float4*)(Ep + co + 4);
        e0.x *= rl; e0.y *= rl; e0.z *= rl; e0.w *= rl;
        e1.x *= rl; e1.y *= rl; e1.z *= rl; e1.w *= rl;
        *(float4*)(Ep + co)     = e0;   // final normalized attn weights
        *(float4*)(Ep + co + 4) = e1;
        short8 ah, al;
        unsigned short h, l;
        cvt_hl(e0.x, h, l); ah[0] = (short)h; al[0] = (short)l;
        cvt_hl(e0.y, h, l); ah[1] = (short)h; al[1] = (short)l;
        cvt_hl(e0.z, h, l); ah[2] = (short)h; al[2] = (short)l;
        cvt_hl(e0.w, h, l); ah[3] = (short)h; al[3] = (short)l;
        cvt_hl(e1.x, h, l); ah[4] = (short)h; al[4] = (short)l;
        cvt_hl(e1.y, h, l); ah[5] = (short)h; al[5] = (short)l;
        cvt_hl(e1.z, h, l); ah[6] = (short)h; al[6] = (short)l;
        cvt_hl(e1.w, h, l); ah[7] = (short)h; al[7] = (short)l;
        short8 bh[8], bl[8];
#pragma unroll
        for (int j = 0; j < 8; ++j) {
            size_t off = vtrow0 + (size_t)(j * 16) * SEQ + co;
            bh[j] = *(const short8*)(VTh + off);
            bl[j] = *(const short8*)(VTl + off);
        }
#pragma unroll
        for (int j = 0; j < 8; ++j) {
            acc[j] = __builtin_amdgcn_mfma_f32_16x16x32_bf16(ah, bh[j], acc[j], 0, 0, 0);
            acc[j] = __builtin_amdgcn_mfma_f32_16x16x32_bf16(ah, bl[j], acc[j], 0, 0, 0);
            acc[j] = __builtin_amdgcn_mfma_f32_16x16x32_bf16(al, bh[j], acc[j], 0, 0, 0);
        }
    }

    float* Ob = O + ((size_t)(b * SEQ + qbase)) * DIM;
#pragma unroll
    for (int j = 0; j < 8; ++j)
#pragma unroll
        for (int r = 0; r < 4; ++r)
            atomicAdd(&Ob[(quad * 4 + r) * DIM + j * 16 + l15], acc[j][r]);
}

extern "C" void kernel_launch(void* const* d_in, const int* in_sizes, int n_in,
                              void* d_out, int out_size, void* d_ws, size_t ws_size,
                              hipStream_t stream) {
    const float* Q = (const float*)d_in[0];
    const float* K = (const float*)d_in[1];
    const float* V = (const float*)d_in[2];
    float* out  = (float*)d_out;
    float* attn = out + (size_t)BATCH * SEQ * DIM;   // outputs concatenated: (out, attn)

    ushort_t* Qh  = (ushort_t*)d_ws;
    ushort_t* Ql  = Qh + (size_t)NEL;
    ushort_t* Kh  = Qh + (size_t)NEL * 2;
    ushort_t* Kl  = Qh + (size_t)NEL * 3;
    ushort_t* VTh = Qh + (size_t)NEL * 4;
    ushort_t* VTl = Qh + (size_t)NEL * 5;
    float* lsum   = (float*)(Qh + (size_t)NEL * 6);  // ws usage: ~50.5 MB

    hipMemsetAsync(lsum, 0, (size_t)BATCH * SEQ * sizeof(float), stream);
    hipMemsetAsync(out, 0, (size_t)BATCH * SEQ * DIM * sizeof(float), stream);
    split_qk_kernel<<<dim3(NEL / 1024), 256, 0, stream>>>(Q, K, Qh, Ql, Kh, Kl);
    split_vt_kernel<<<dim3(32, 2, 16), 256, 0, stream>>>(V, VTh, VTl);
    attn_scores_kernel<<<dim3(16, 16, 16), 256, 0, stream>>>(Qh, Ql, Kh, Kl, attn, lsum);
    attn_out_kernel<<<dim3(32, 2, 16), 256, 0, stream>>>(VTh, VTl, attn, lsum, out);
}